// Round 1
// baseline (30448.297 us; speedup 1.0000x reference)
//
#include <hip/hip_runtime.h>
#include <math.h>

// Problem constants
#define Lsteps 5
#define Bn 8
#define Hn 256
#define Wn 256
#define HWn 65536           // 256*256
#define BHW 524288          // 8*65536
#define HID 100

// d_out float offsets
#define OUT_IMG    0
#define OUT_FIELDS 524288
#define OUT_RES    5767168
#define OUT_GRADS  8912896

// workspace float offsets
#define WS_IMG  0            // 524288
#define WS_PHIA 524288       // 5242880  [5][8][256][256][2]
#define WS_PHIB 5767168      // 5242880
#define WS_VTMP 11010048     // 1048576  [8][2][256][256]
#define WS_W2T  12058624     // 450000   [5][100][9][100]

__device__ inline void make_gauss(float* G) {
  float s = 0.f;
#pragma unroll
  for (int t = 0; t < 15; t++) {
    float d = (float)t - 7.f;
    G[t] = expf(-d * d * (1.f / 32.f));
    s += G[t];
  }
  float inv = 1.f / s;
#pragma unroll
  for (int t = 0; t < 15; t++) G[t] *= inv;
}

__device__ inline float bilin1(const float* __restrict__ p, float x, float y) {
  float x0f = floorf(x), y0f = floorf(y);
  int x0 = (int)x0f, y0 = (int)y0f;
  float fx = x - x0f, fy = y - y0f;
  float w00 = (1.f - fx) * (1.f - fy), w10 = fx * (1.f - fy);
  float w01 = (1.f - fx) * fy, w11 = fx * fy;
  float acc = 0.f;
  if ((unsigned)x0 < 256u && (unsigned)y0 < 256u) acc += w00 * p[y0 * 256 + x0];
  if ((unsigned)(x0 + 1) < 256u && (unsigned)y0 < 256u) acc += w10 * p[y0 * 256 + x0 + 1];
  if ((unsigned)x0 < 256u && (unsigned)(y0 + 1) < 256u) acc += w01 * p[(y0 + 1) * 256 + x0];
  if ((unsigned)(x0 + 1) < 256u && (unsigned)(y0 + 1) < 256u) acc += w11 * p[(y0 + 1) * 256 + x0 + 1];
  return acc;
}

__device__ inline void bilin2(const float* __restrict__ p, float x, float y,
                              float& o0, float& o1) {
  float x0f = floorf(x), y0f = floorf(y);
  int x0 = (int)x0f, y0 = (int)y0f;
  float fx = x - x0f, fy = y - y0f;
  float w00 = (1.f - fx) * (1.f - fy), w10 = fx * (1.f - fy);
  float w01 = (1.f - fx) * fy, w11 = fx * fy;
  o0 = 0.f; o1 = 0.f;
  if ((unsigned)x0 < 256u && (unsigned)y0 < 256u) {
    const float* q = p + (y0 * 256 + x0) * 2; o0 += w00 * q[0]; o1 += w00 * q[1];
  }
  if ((unsigned)(x0 + 1) < 256u && (unsigned)y0 < 256u) {
    const float* q = p + (y0 * 256 + x0 + 1) * 2; o0 += w10 * q[0]; o1 += w10 * q[1];
  }
  if ((unsigned)x0 < 256u && (unsigned)(y0 + 1) < 256u) {
    const float* q = p + ((y0 + 1) * 256 + x0) * 2; o0 += w01 * q[0]; o1 += w01 * q[1];
  }
  if ((unsigned)(x0 + 1) < 256u && (unsigned)(y0 + 1) < 256u) {
    const float* q = p + ((y0 + 1) * 256 + x0 + 1) * 2; o0 += w11 * q[0]; o1 += w11 * q[1];
  }
}

__global__ void init_res0_kernel(const float* __restrict__ z0, float* __restrict__ res0) {
  int idx = blockIdx.x * 256 + threadIdx.x;   // 524288 total
  res0[idx] = z0[idx & 65535];
}

__global__ void w2t_kernel(const float* __restrict__ w2, float* __restrict__ w2t) {
  int idx = blockIdx.x * 256 + threadIdx.x;
  if (idx >= Lsteps * 100 * 100 * 9) return;
  int l = idx / 90000;
  int r = idx - l * 90000;
  int oc = r / 900;
  int r2 = r - oc * 900;
  int ic = r2 / 9;
  int j = r2 - ic * 9;
  w2t[l * 90000 + (ic * 9 + j) * 100 + oc] = w2[idx];
}

__global__ void sobel_kernel(const float* __restrict__ img, float* __restrict__ gout) {
  int idx = blockIdx.x * 256 + threadIdx.x;   // 524288
  int b = idx >> 16; int y = (idx >> 8) & 255; int x = idx & 255;
  const float* p = img + b * HWn;
  int ym = y > 0 ? y - 1 : 0, yp = y < 255 ? y + 1 : 255;
  int xm = x > 0 ? x - 1 : 0, xp = x < 255 ? x + 1 : 255;
  float a00 = p[ym * 256 + xm], a01 = p[ym * 256 + x], a02 = p[ym * 256 + xp];
  float a10 = p[y * 256 + xm], a12 = p[y * 256 + xp];
  float a20 = p[yp * 256 + xm], a21 = p[yp * 256 + x], a22 = p[yp * 256 + xp];
  float gx = (a02 - a00 + 2.f * (a12 - a10) + a22 - a20) * 0.125f;
  float gy = (a20 - a00 + 2.f * (a21 - a01) + a22 - a02) * 0.125f;
  gout[b * 131072 + y * 256 + x] = gx;
  gout[b * 131072 + 65536 + y * 256 + x] = gy;
}

// vtmp[b,c,y,x] = sum_t G[t] * (-res[b,y+t-7,x] * g[b,c,y+t-7,x]), zero pad in y
__global__ void vblur_rg_kernel(const float* __restrict__ res_i, const float* __restrict__ g,
                                float* __restrict__ vtmp) {
  int idx = blockIdx.x * 256 + threadIdx.x;   // 1048576
  int b = idx >> 17;
  int c = (idx >> 16) & 1;
  int y = (idx >> 8) & 255;
  int x = idx & 255;
  float G[15]; make_gauss(G);
  const float* rb = res_i + b * HWn;
  const float* gb = g + b * 131072 + c * 65536;
  float s = 0.f;
#pragma unroll
  for (int t = 0; t < 15; t++) {
    int yy = y + t - 7;
    if ((unsigned)yy < 256u) {
      int o = yy * 256 + x;
      s += G[t] * (-rb[o] * gb[o]);
    }
  }
  vtmp[idx] = s;
}

// fields[b,y,x,c] = sum_t G[t] * vtmp[b,c,y,x+t-7], zero pad in x  (NHWC transpose)
__global__ void hblur_kernel(const float* __restrict__ vtmp, float* __restrict__ fields_i) {
  int idx = blockIdx.x * 256 + threadIdx.x;   // 1048576
  int b = idx >> 17;
  int c = (idx >> 16) & 1;
  int y = (idx >> 8) & 255;
  int x = idx & 255;
  float G[15]; make_gauss(G);
  const float* vb = vtmp + b * 131072 + c * 65536 + y * 256;
  float s = 0.f;
#pragma unroll
  for (int t = 0; t < 15; t++) {
    int xx = x + t - 7;
    if ((unsigned)xx < 256u) s += G[t] * vb[xx];
  }
  fields_i[((b * 65536) + (y * 256) + x) * 2 + c] = s;
}

// Fully fused res_block: conv1(3->100)+lrelu in LDS, conv2(100->100)+lrelu streamed
// in chunks of 10 oc, conv3(100->1) accumulated. Writes res_next = res_i - f/L.
// 14x14 output tile per block, 256 threads, 1 block/CU (≈140 KB LDS).
__global__ __launch_bounds__(256, 1) void resblock_kernel(
    const float* __restrict__ res_i, const float* __restrict__ img,
    const float* __restrict__ tgt, const float* __restrict__ w1,
    const float* __restrict__ w2t, const float* __restrict__ w3,
    float* __restrict__ res_next) {
  __shared__ float x1s[100 * 324];   // [ic][18][18], 129600 B
  __shared__ float x2s[10 * 256];    // [c][16][16], 10240 B
  const int tid = threadIdx.x;
  const int b = blockIdx.z;
  const int tY0 = blockIdx.y * 14, tX0 = blockIdx.x * 14;
  const float* zb = res_i + b * HWn;
  const float* ib = img + b * HWn;
  const float* tb = tgt + b * HWn;

  // Phase A: conv1 + lrelu into x1s (zero for out-of-image halo)
  for (int pos = tid; pos < 324; pos += 256) {
    int ly = pos / 18;
    int lx = pos - ly * 18;
    int gy = tY0 + ly - 2, gx = tX0 + lx - 2;
    bool inb = (unsigned)gy < 256u && (unsigned)gx < 256u;
    float patch[27];
#pragma unroll
    for (int dy = 0; dy < 3; dy++) {
      int yy = gy + dy - 1;
      bool oky = (unsigned)yy < 256u;
#pragma unroll
      for (int dx = 0; dx < 3; dx++) {
        int xx = gx + dx - 1;
        bool ok = oky && (unsigned)xx < 256u;
        int o = yy * 256 + xx;
        int j = dy * 3 + dx;
        patch[j] = ok ? zb[o] : 0.f;
        patch[9 + j] = ok ? ib[o] : 0.f;
        patch[18 + j] = ok ? tb[o] : 0.f;
      }
    }
    for (int oc = 0; oc < 100; oc++) {
      const float* w = w1 + oc * 27;
      float s = 0.f;
#pragma unroll
      for (int j = 0; j < 27; j++) s = fmaf(patch[j], w[j], s);
      s = s > 0.f ? s : 0.01f * s;
      x1s[oc * 324 + pos] = inb ? s : 0.f;
    }
  }
  __syncthreads();

  const int xy = tid >> 4, xx = tid & 15;        // x2 tile coord (16x16)
  const int fy = tid / 14, fx = tid - fy * 14;   // f tile coord, valid tid<196
  const bool fok = tid < 196;
  const int fgy = tY0 + fy, fgx = tX0 + fx;
  const bool fin = fok && fgy < 256 && fgx < 256;
  const int x2gy = tY0 + xy - 1, x2gx = tX0 + xx - 1;
  const bool in2 = (unsigned)x2gy < 256u && (unsigned)x2gx < 256u;
  float facc = 0.f;

  for (int oc0 = 0; oc0 < 100; oc0 += 10) {
    float acc[10];
#pragma unroll
    for (int c = 0; c < 10; c++) acc[c] = 0.f;
    const float* wbase = w2t + oc0;
    for (int ic = 0; ic < 100; ic++) {
      const float* xp = &x1s[ic * 324 + xy * 18 + xx];
      float p[9];
      p[0] = xp[0];  p[1] = xp[1];  p[2] = xp[2];
      p[3] = xp[18]; p[4] = xp[19]; p[5] = xp[20];
      p[6] = xp[36]; p[7] = xp[37]; p[8] = xp[38];
      const float* wt = wbase + ic * 900;
#pragma unroll
      for (int j = 0; j < 9; j++) {
        const float* wj = wt + j * 100;
#pragma unroll
        for (int c = 0; c < 10; c++) acc[c] = fmaf(p[j], wj[c], acc[c]);
      }
    }
#pragma unroll
    for (int c = 0; c < 10; c++) {
      float v = acc[c];
      v = v > 0.f ? v : 0.01f * v;
      x2s[c * 256 + tid] = in2 ? v : 0.f;
    }
    __syncthreads();
    if (fok) {
#pragma unroll
      for (int c = 0; c < 10; c++) {
        const float* w3c = w3 + (oc0 + c) * 9;
        float s = 0.f;
#pragma unroll
        for (int dy = 0; dy < 3; dy++)
#pragma unroll
          for (int dx = 0; dx < 3; dx++)
            s = fmaf(x2s[c * 256 + (fy + dy) * 16 + (fx + dx)], w3c[dy * 3 + dx], s);
        facc += s;
      }
    }
    __syncthreads();
  }

  if (fin) {
    int o = b * HWn + fgy * 256 + fgx;
    res_next[o] = zb[fgy * 256 + fgx] - facc * 0.2f;
  }
}

// For k<step: phi_dst[k] = bilinear(phi_src[k], deformation); k==step: phi_dst[k]=deformation
__global__ void phi_update_kernel(const float* __restrict__ fields_i,
                                  const float* __restrict__ phi_src,
                                  float* __restrict__ phi_dst, int step) {
  int idx = blockIdx.x * 256 + threadIdx.x;   // (step+1)*524288
  int k = idx >> 19;
  int r = idx & 524287;
  int b = r >> 16;
  int y = (r >> 8) & 255;
  int x = r & 255;
  float f0 = fields_i[2 * r], f1 = fields_i[2 * r + 1];
  float dx = (float)x - f0 * 0.2f;
  float dy = (float)y - f1 * 0.2f;
  float o0, o1;
  if (k == step) { o0 = dx; o1 = dy; }
  else bilin2(phi_src + (size_t)(k * 8 + b) * 131072, dx, dy, o0, o1);
  float* dst = phi_dst + (size_t)(k * 8 + b) * 131072 + (y * 256 + x) * 2;
  dst[0] = o0; dst[1] = o1;
}

// image = warp(source, phi[0]) + (res[step+1] + sum_{k=1..step} warp(res[k], phi[k])) * MU^2/L
__global__ void image_update_kernel(const float* __restrict__ source,
                                    const float* __restrict__ res_sec,
                                    const float* __restrict__ phi_cur, int step,
                                    float* __restrict__ img_out) {
  int idx = blockIdx.x * 256 + threadIdx.x;   // 524288
  int b = idx >> 16;
  int y = (idx >> 8) & 255;
  int x = idx & 255;
  int pix2 = (y * 256 + x) * 2;
  const float* ph0 = phi_cur + (size_t)b * 131072 + pix2;
  float img = bilin1(source + b * HWn, ph0[0], ph0[1]);
  float rs = res_sec[(step + 1) * BHW + idx];
  for (int k = 1; k <= step; k++) {
    const float* ph = phi_cur + (size_t)(k * 8 + b) * 131072 + pix2;
    rs += bilin1(res_sec + k * BHW + b * HWn, ph[0], ph[1]);
  }
  img_out[idx] = img + rs * 8.0e-5f;
}

extern "C" void kernel_launch(void* const* d_in, const int* in_sizes, int n_in,
                              void* d_out, int out_size, void* d_ws, size_t ws_size,
                              hipStream_t stream) {
  const float* source = (const float*)d_in[0];
  const float* target = (const float*)d_in[1];
  // d_in[2] = source_seg (unused by reference)
  const float* z0 = (const float*)d_in[3];
  const float* w1 = (const float*)d_in[4];
  const float* w2 = (const float*)d_in[5];
  const float* w3 = (const float*)d_in[6];
  float* out = (float*)d_out;
  float* ws = (float*)d_ws;

  float* ws_img = ws + WS_IMG;
  float* phiA = ws + WS_PHIA;
  float* phiB = ws + WS_PHIB;
  float* vtmp = ws + WS_VTMP;
  float* w2t = ws + WS_W2T;

  // image = source; residuals[0] = broadcast(z0); transpose w2 once
  hipMemcpyAsync(ws_img, source, BHW * sizeof(float), hipMemcpyDeviceToDevice, stream);
  init_res0_kernel<<<BHW / 256, 256, 0, stream>>>(z0, out + OUT_RES);
  w2t_kernel<<<(Lsteps * 90000 + 255) / 256, 256, 0, stream>>>(w2, w2t);

  for (int i = 0; i < Lsteps; i++) {
    float* grads_i = out + OUT_GRADS + (size_t)i * 1048576;
    float* fields_i = out + OUT_FIELDS + (size_t)i * 1048576;
    const float* res_i = out + OUT_RES + (size_t)i * BHW;
    float* res_n = out + OUT_RES + (size_t)(i + 1) * BHW;
    float* phi_dst = (i % 2 == 0) ? phiA : phiB;
    float* phi_src = (i % 2 == 0) ? phiB : phiA;

    sobel_kernel<<<BHW / 256, 256, 0, stream>>>(ws_img, grads_i);
    vblur_rg_kernel<<<1048576 / 256, 256, 0, stream>>>(res_i, grads_i, vtmp);
    hblur_kernel<<<1048576 / 256, 256, 0, stream>>>(vtmp, fields_i);
    resblock_kernel<<<dim3(19, 19, 8), 256, 0, stream>>>(
        res_i, ws_img, target, w1 + i * 2700, w2t + i * 90000, w3 + i * 900, res_n);
    phi_update_kernel<<<(i + 1) * (BHW / 256), 256, 0, stream>>>(fields_i, phi_src, phi_dst, i);
    image_update_kernel<<<BHW / 256, 256, 0, stream>>>(source, out + OUT_RES, phi_dst, i, ws_img);
  }
  hipMemcpyAsync(out + OUT_IMG, ws_img, BHW * sizeof(float), hipMemcpyDeviceToDevice, stream);
}

// Round 4
// 5108.417 us; speedup vs baseline: 5.9604x; 5.9604x over previous
//
#include <hip/hip_runtime.h>
#include <math.h>

typedef __attribute__((ext_vector_type(8))) short short8;
typedef __attribute__((ext_vector_type(4))) float f32x4;
typedef unsigned int uint;
typedef unsigned short ushort;

// Problem constants
#define Lsteps 5
#define Hn 256
#define Wn 256
#define HWn 65536           // 256*256
#define BHW 524288          // 8*65536

// d_out float offsets
#define OUT_IMG    0
#define OUT_FIELDS 524288
#define OUT_RES    5767168
#define OUT_GRADS  8912896

// workspace float offsets
#define WS_IMG  0            // 524288
#define WS_PHIA 524288       // 5242880  [5][8][256][256][2]
#define WS_PHIB 5767168      // 5242880
#define WS_VTMP 11010048     // 1048576  [8][2][256][256]
#define WS_W2H  12058624     // 368640 f (737280 ushort)  [5][9][128 oc][128 ic] bf16 hi
#define WS_W2L  12427264     // 368640 f                   bf16 lo
#define WS_W3P  12795904     // 5760 f  [5][9][128 ic] fp32
#define WS_X2F  12801664     // 13631488 f  [2][65536 px][104 ch] fp32 (per-2-batch)

__device__ inline float lrelu(float s) { return s > 0.f ? s : 0.01f * s; }

__device__ inline ushort bf16r(float f) {
  uint u = __float_as_uint(f);
  return (ushort)((u + 0x7fffu + ((u >> 16) & 1u)) >> 16);
}
__device__ inline float bf2f(ushort h) { return __uint_as_float(((uint)h) << 16); }

__device__ inline void make_gauss(float* G) {
  float s = 0.f;
#pragma unroll
  for (int t = 0; t < 15; t++) {
    float d = (float)t - 7.f;
    G[t] = expf(-d * d * (1.f / 32.f));
    s += G[t];
  }
  float inv = 1.f / s;
#pragma unroll
  for (int t = 0; t < 15; t++) G[t] *= inv;
}

__device__ inline float bilin1(const float* __restrict__ p, float x, float y) {
  float x0f = floorf(x), y0f = floorf(y);
  int x0 = (int)x0f, y0 = (int)y0f;
  float fx = x - x0f, fy = y - y0f;
  float w00 = (1.f - fx) * (1.f - fy), w10 = fx * (1.f - fy);
  float w01 = (1.f - fx) * fy, w11 = fx * fy;
  float acc = 0.f;
  if ((unsigned)x0 < 256u && (unsigned)y0 < 256u) acc += w00 * p[y0 * 256 + x0];
  if ((unsigned)(x0 + 1) < 256u && (unsigned)y0 < 256u) acc += w10 * p[y0 * 256 + x0 + 1];
  if ((unsigned)x0 < 256u && (unsigned)(y0 + 1) < 256u) acc += w01 * p[(y0 + 1) * 256 + x0];
  if ((unsigned)(x0 + 1) < 256u && (unsigned)(y0 + 1) < 256u) acc += w11 * p[(y0 + 1) * 256 + x0 + 1];
  return acc;
}

__device__ inline void bilin2(const float* __restrict__ p, float x, float y,
                              float& o0, float& o1) {
  float x0f = floorf(x), y0f = floorf(y);
  int x0 = (int)x0f, y0 = (int)y0f;
  float fx = x - x0f, fy = y - y0f;
  float w00 = (1.f - fx) * (1.f - fy), w10 = fx * (1.f - fy);
  float w01 = (1.f - fx) * fy, w11 = fx * fy;
  o0 = 0.f; o1 = 0.f;
  if ((unsigned)x0 < 256u && (unsigned)y0 < 256u) {
    const float* q = p + (y0 * 256 + x0) * 2; o0 += w00 * q[0]; o1 += w00 * q[1];
  }
  if ((unsigned)(x0 + 1) < 256u && (unsigned)y0 < 256u) {
    const float* q = p + (y0 * 256 + x0 + 1) * 2; o0 += w10 * q[0]; o1 += w10 * q[1];
  }
  if ((unsigned)x0 < 256u && (unsigned)(y0 + 1) < 256u) {
    const float* q = p + ((y0 + 1) * 256 + x0) * 2; o0 += w01 * q[0]; o1 += w01 * q[1];
  }
  if ((unsigned)(x0 + 1) < 256u && (unsigned)(y0 + 1) < 256u) {
    const float* q = p + ((y0 + 1) * 256 + x0 + 1) * 2; o0 += w11 * q[0]; o1 += w11 * q[1];
  }
}

__global__ void init_res0_kernel(const float* __restrict__ z0, float* __restrict__ res0) {
  int idx = blockIdx.x * 256 + threadIdx.x;
  res0[idx] = z0[idx & 65535];
}

// w2 hi/lo bf16 split: [l][tap][oc][ic], oc/ic zero-padded to 128
__global__ void w2p_prep(const float* __restrict__ w2, ushort* __restrict__ w2h,
                         ushort* __restrict__ w2l) {
  int idx = blockIdx.x * 256 + threadIdx.x;     // 737280
  int l = idx / 147456;
  int r = idx - l * 147456;
  int tap = r >> 14;
  int r2 = r & 16383;
  int oc = r2 >> 7;
  int ic = r2 & 127;
  float v = (oc < 100 && ic < 100) ? w2[l * 90000 + oc * 900 + ic * 9 + tap] : 0.f;
  ushort hi = bf16r(v);
  w2h[idx] = hi;
  w2l[idx] = bf16r(v - bf2f(hi));
}

// w3p[l][tap][ic] fp32, ic zero-padded to 128
__global__ void w3p_prep(const float* __restrict__ w3, float* __restrict__ w3p) {
  int idx = blockIdx.x * 256 + threadIdx.x;     // 5760
  if (idx >= Lsteps * 9 * 128) return;
  int l = idx / 1152;
  int r = idx - l * 1152;
  int tap = r >> 7;
  int ic = r & 127;
  w3p[idx] = (ic < 100) ? w3[l * 900 + ic * 9 + tap] : 0.f;
}

__global__ void sobel_kernel(const float* __restrict__ img, float* __restrict__ gout) {
  int idx = blockIdx.x * 256 + threadIdx.x;
  int b = idx >> 16; int y = (idx >> 8) & 255; int x = idx & 255;
  const float* p = img + b * HWn;
  int ym = y > 0 ? y - 1 : 0, yp = y < 255 ? y + 1 : 255;
  int xm = x > 0 ? x - 1 : 0, xp = x < 255 ? x + 1 : 255;
  float a00 = p[ym * 256 + xm], a01 = p[ym * 256 + x], a02 = p[ym * 256 + xp];
  float a10 = p[y * 256 + xm], a12 = p[y * 256 + xp];
  float a20 = p[yp * 256 + xm], a21 = p[yp * 256 + x], a22 = p[yp * 256 + xp];
  float gx = (a02 - a00 + 2.f * (a12 - a10) + a22 - a20) * 0.125f;
  float gy = (a20 - a00 + 2.f * (a21 - a01) + a22 - a02) * 0.125f;
  gout[b * 131072 + y * 256 + x] = gx;
  gout[b * 131072 + 65536 + y * 256 + x] = gy;
}

__global__ void vblur_rg_kernel(const float* __restrict__ res_i, const float* __restrict__ g,
                                float* __restrict__ vtmp) {
  int idx = blockIdx.x * 256 + threadIdx.x;
  int b = idx >> 17;
  int c = (idx >> 16) & 1;
  int y = (idx >> 8) & 255;
  int x = idx & 255;
  float G[15]; make_gauss(G);
  const float* rb = res_i + b * HWn;
  const float* gb = g + b * 131072 + c * 65536;
  float s = 0.f;
#pragma unroll
  for (int t = 0; t < 15; t++) {
    int yy = y + t - 7;
    if ((unsigned)yy < 256u) {
      int o = yy * 256 + x;
      s += G[t] * (-rb[o] * gb[o]);
    }
  }
  vtmp[idx] = s;
}

__global__ void hblur_kernel(const float* __restrict__ vtmp, float* __restrict__ fields_i) {
  int idx = blockIdx.x * 256 + threadIdx.x;
  int b = idx >> 17;
  int c = (idx >> 16) & 1;
  int y = (idx >> 8) & 255;
  int x = idx & 255;
  float G[15]; make_gauss(G);
  const float* vb = vtmp + b * 131072 + c * 65536 + y * 256;
  float s = 0.f;
#pragma unroll
  for (int t = 0; t < 15; t++) {
    int xx = x + t - 7;
    if ((unsigned)xx < 256u) s += G[t] * vb[xx];
  }
  fields_i[((b * 65536) + (y * 256) + x) * 2 + c] = s;
}

// Fused conv1 (fp32 VALU -> hi/lo bf16 LDS) + conv2 (3-term split-bf16 MFMA ~ fp32).
// Block: 16x8 pixel tile, 256 threads. Covers 2 batches via blockIdx.z.
// LDS: x1h/x1l [180][136] 2x48.96KB + wlds [2][128][40] 20.5KB = 118.4KB -> 1 block/CU.
__global__ __launch_bounds__(256, 1) void conv12_kernel(
    const float* __restrict__ res_i, const float* __restrict__ img,
    const float* __restrict__ tgt, const float* __restrict__ w1,
    const ushort* __restrict__ w2h, const ushort* __restrict__ w2l,
    float* __restrict__ x2f, int b0) {
  __shared__ ushort x1h[180 * 136];
  __shared__ ushort x1l[180 * 136];
  __shared__ ushort wlds[2 * 128 * 40];
  const int tid = threadIdx.x;
  const int bb = blockIdx.z;
  const int b = b0 + bb;
  const int Y0 = blockIdx.y * 8, X0 = blockIdx.x * 16;
  const float* zb = res_i + b * HWn;
  const float* ib = img + b * HWn;
  const float* tb = tgt + b * HWn;

  // ---- Phase A: conv1 (3->100) + lrelu -> hi/lo bf16 in LDS ----
  // x1 (conv1 output) exists only on the 256x256 image grid; conv2 zero-pads
  // outside it, so halo positions beyond the image MUST be stored as zero.
  if (tid < 180) {
    int ly = tid / 18, lx = tid - ly * 18;
    int gy = Y0 + ly - 1, gx = X0 + lx - 1;
    const bool inb = (unsigned)gy < 256u && (unsigned)gx < 256u;
    float p[27];
#pragma unroll
    for (int dy = 0; dy < 3; dy++)
#pragma unroll
      for (int dx = 0; dx < 3; dx++) {
        int yy = gy + dy - 1, xx = gx + dx - 1;
        bool ok = (unsigned)yy < 256u && (unsigned)xx < 256u;
        int o = ok ? (yy * 256 + xx) : 0;
        int j = dy * 3 + dx;
        p[j] = ok ? zb[o] : 0.f;
        p[9 + j] = ok ? ib[o] : 0.f;
        p[18 + j] = ok ? tb[o] : 0.f;
      }
    const uint base = (uint)tid * 136u;
    for (int oc = 0; oc < 100; oc++) {
      const float* wa = w1 + oc * 27;
      float s = 0.f;
#pragma unroll
      for (int j = 0; j < 27; j++) s = fmaf(p[j], wa[j], s);
      s = inb ? lrelu(s) : 0.f;
      ushort hi = bf16r(s);
      x1h[base + oc] = hi;
      x1l[base + oc] = bf16r(s - bf2f(hi));
    }
#pragma unroll
    for (int oc = 100; oc < 128; oc++) { x1h[base + oc] = 0; x1l[base + oc] = 0; }
  }

  // ---- Phase B: conv2 via 3-term split MFMA ----
  const int lane = tid & 63, wv = tid >> 6;
  const int q = lane >> 4, n = lane & 15;
  f32x4 acc[2][7];
#pragma unroll
  for (int r = 0; r < 2; r++)
#pragma unroll
    for (int o = 0; o < 7; o++) acc[r][o] = (f32x4)(0.f);

  for (int tap = 0; tap < 9; tap++) {
    const int dy = tap / 3, dx = tap - dy * 3;
    for (int kc = 0; kc < 4; kc++) {
      __syncthreads();
      // stage W chunk [2(hi/lo)][128 oc][32 ic] for (tap,kc)
#pragma unroll
      for (int it = 0; it < 4; it++) {
        int idx = it * 256 + tid;   // 0..1023
        int t = idx >> 9;
        int r2 = idx & 511;
        int oc = r2 >> 2, c = r2 & 3;
        const ushort* src = (t ? w2l : w2h) + tap * 16384 + oc * 128 + kc * 32 + c * 8;
        *(uint4*)&wlds[t * 5120 + oc * 40 + c * 8] = *(const uint4*)src;
      }
      __syncthreads();
      const int ko = q * 8;
      short8 ah[2], al[2], bh[7], bl[7];
#pragma unroll
      for (int r = 0; r < 2; r++) {
        uint off = (uint)((wv * 2 + r + dy) * 18 + n + dx) * 136u + kc * 32 + ko;
        ah[r] = *(const short8*)&x1h[off];
        al[r] = *(const short8*)&x1l[off];
      }
#pragma unroll
      for (int o = 0; o < 7; o++) {
        bh[o] = *(const short8*)&wlds[(o * 16 + n) * 40 + ko];
        bl[o] = *(const short8*)&wlds[5120 + (o * 16 + n) * 40 + ko];
      }
#pragma unroll
      for (int r = 0; r < 2; r++)
#pragma unroll
        for (int o = 0; o < 7; o++) {
          acc[r][o] = __builtin_amdgcn_mfma_f32_16x16x32_bf16(ah[r], bh[o], acc[r][o], 0, 0, 0);
          acc[r][o] = __builtin_amdgcn_mfma_f32_16x16x32_bf16(ah[r], bl[o], acc[r][o], 0, 0, 0);
          acc[r][o] = __builtin_amdgcn_mfma_f32_16x16x32_bf16(al[r], bh[o], acc[r][o], 0, 0, 0);
        }
    }
  }

  // ---- Epilogue: lrelu -> fp32 x2f [bb][px][104] ----
#pragma unroll
  for (int r = 0; r < 2; r++) {
    int y = Y0 + wv * 2 + r;
#pragma unroll
    for (int o = 0; o < 7; o++) {
      if (o == 6 && n >= 8) continue;
      int oc = o * 16 + n;
#pragma unroll
      for (int v = 0; v < 4; v++) {
        int x = X0 + q * 4 + v;
        x2f[(size_t)((bb << 16) + y * 256 + x) * 104 + oc] = lrelu(acc[r][o][v]);
      }
    }
  }
}

// conv3 (100->1) fp32 over fp32 x2f, fused residual update. Covers 2 batches.
__global__ void conv3_kernel(const float* __restrict__ res_i,
                             const float* __restrict__ x2f,
                             const float* __restrict__ w3p,
                             float* __restrict__ res_n, int b0) {
  int idx = blockIdx.x * 256 + threadIdx.x;   // 131072
  int bb = idx >> 16, y = (idx >> 8) & 255, x = idx & 255;
  int b = b0 + bb;
  float acc = 0.f;
#pragma unroll
  for (int tap = 0; tap < 9; tap++) {
    int dy = tap / 3, dx = tap - dy * 3;
    int yy = y + dy - 1, xx = x + dx - 1;
    if ((unsigned)yy < 256u && (unsigned)xx < 256u) {
      const float* px = x2f + (size_t)((bb << 16) + yy * 256 + xx) * 104;
      const float* wt = w3p + tap * 128;
#pragma unroll
      for (int c = 0; c < 26; c++) {
        f32x4 u = *(const f32x4*)(px + c * 4);
        const float* w4 = wt + c * 4;
        acc = fmaf(u.x, w4[0], acc);
        acc = fmaf(u.y, w4[1], acc);
        acc = fmaf(u.z, w4[2], acc);
        acc = fmaf(u.w, w4[3], acc);
      }
    }
  }
  int o = (b << 16) + (idx & 65535);
  res_n[o] = res_i[o] - 0.2f * acc;
}

__global__ void phi_update_kernel(const float* __restrict__ fields_i,
                                  const float* __restrict__ phi_src,
                                  float* __restrict__ phi_dst, int step) {
  int idx = blockIdx.x * 256 + threadIdx.x;
  int k = idx >> 19;
  int r = idx & 524287;
  int b = r >> 16;
  int y = (r >> 8) & 255;
  int x = r & 255;
  float f0 = fields_i[2 * r], f1 = fields_i[2 * r + 1];
  float dx = (float)x - f0 * 0.2f;
  float dy = (float)y - f1 * 0.2f;
  float o0, o1;
  if (k == step) { o0 = dx; o1 = dy; }
  else bilin2(phi_src + (size_t)(k * 8 + b) * 131072, dx, dy, o0, o1);
  float* dst = phi_dst + (size_t)(k * 8 + b) * 131072 + (y * 256 + x) * 2;
  dst[0] = o0; dst[1] = o1;
}

__global__ void image_update_kernel(const float* __restrict__ source,
                                    const float* __restrict__ res_sec,
                                    const float* __restrict__ phi_cur, int step,
                                    float* __restrict__ img_out) {
  int idx = blockIdx.x * 256 + threadIdx.x;
  int b = idx >> 16;
  int y = (idx >> 8) & 255;
  int x = idx & 255;
  int pix2 = (y * 256 + x) * 2;
  const float* ph0 = phi_cur + (size_t)b * 131072 + pix2;
  float img = bilin1(source + b * HWn, ph0[0], ph0[1]);
  float rs = res_sec[(step + 1) * BHW + idx];
  for (int k = 1; k <= step; k++) {
    const float* ph = phi_cur + (size_t)(k * 8 + b) * 131072 + pix2;
    rs += bilin1(res_sec + k * BHW + b * HWn, ph[0], ph[1]);
  }
  img_out[idx] = img + rs * 8.0e-5f;
}

extern "C" void kernel_launch(void* const* d_in, const int* in_sizes, int n_in,
                              void* d_out, int out_size, void* d_ws, size_t ws_size,
                              hipStream_t stream) {
  const float* source = (const float*)d_in[0];
  const float* target = (const float*)d_in[1];
  const float* z0 = (const float*)d_in[3];
  const float* w1 = (const float*)d_in[4];
  const float* w2 = (const float*)d_in[5];
  const float* w3 = (const float*)d_in[6];
  float* out = (float*)d_out;
  float* ws = (float*)d_ws;

  float* ws_img = ws + WS_IMG;
  float* phiA = ws + WS_PHIA;
  float* phiB = ws + WS_PHIB;
  float* vtmp = ws + WS_VTMP;
  ushort* w2h = (ushort*)(ws + WS_W2H);
  ushort* w2l = (ushort*)(ws + WS_W2L);
  float* w3p = ws + WS_W3P;
  float* x2f = ws + WS_X2F;

  hipMemcpyAsync(ws_img, source, BHW * sizeof(float), hipMemcpyDeviceToDevice, stream);
  init_res0_kernel<<<BHW / 256, 256, 0, stream>>>(z0, out + OUT_RES);
  w2p_prep<<<737280 / 256, 256, 0, stream>>>(w2, w2h, w2l);
  w3p_prep<<<23, 256, 0, stream>>>(w3, w3p);

  for (int i = 0; i < Lsteps; i++) {
    float* grads_i = out + OUT_GRADS + (size_t)i * 1048576;
    float* fields_i = out + OUT_FIELDS + (size_t)i * 1048576;
    const float* res_i = out + OUT_RES + (size_t)i * BHW;
    float* res_n = out + OUT_RES + (size_t)(i + 1) * BHW;
    float* phi_dst = (i % 2 == 0) ? phiA : phiB;
    float* phi_src = (i % 2 == 0) ? phiB : phiA;

    sobel_kernel<<<BHW / 256, 256, 0, stream>>>(ws_img, grads_i);
    vblur_rg_kernel<<<1048576 / 256, 256, 0, stream>>>(res_i, grads_i, vtmp);
    hblur_kernel<<<1048576 / 256, 256, 0, stream>>>(vtmp, fields_i);
    for (int b0 = 0; b0 < 8; b0 += 2) {
      conv12_kernel<<<dim3(16, 32, 2), 256, 0, stream>>>(
          res_i, ws_img, target, w1 + i * 2700, w2h + (size_t)i * 147456,
          w2l + (size_t)i * 147456, x2f, b0);
      conv3_kernel<<<512, 256, 0, stream>>>(res_i, x2f, w3p + i * 1152, res_n, b0);
    }
    phi_update_kernel<<<(i + 1) * (BHW / 256), 256, 0, stream>>>(fields_i, phi_src, phi_dst, i);
    image_update_kernel<<<BHW / 256, 256, 0, stream>>>(source, out + OUT_RES, phi_dst, i, ws_img);
  }
  hipMemcpyAsync(out + OUT_IMG, ws_img, BHW * sizeof(float), hipMemcpyDeviceToDevice, stream);
}